// Round 16
// baseline (3444.197 us; speedup 1.0000x reference)
//
#include <hip/hip_runtime.h>

#define NF 32
#define HDIM 256
#define SLEN 256
#define BATCH 1024

typedef float f32x4 __attribute__((ext_vector_type(4)));
typedef __bf16 bf16x8 __attribute__((ext_vector_type(8)));
typedef unsigned short u16;

#define MFMA __builtin_amdgcn_mfma_f32_16x16x32_bf16
#define BC(x) __builtin_bit_cast(bf16x8, x)

// ---- ws layout ----
#define WHH_O 0       // 64 j * 8 t * 64 l  = 32768 slots
#define WIH_O 32768   // 64 j * 64 l        =  4096
#define WOUT_O 36864  //  2 j * 8 t * 64 l  =  1024
#define WLAT_O 37888  // 32 j * 2 t * 64 l  =  4096
#define PREP1_N 41984
#define WT_BYTE (1u << 20)
#define HST_BYTE (8u << 20)

__device__ __forceinline__ u16 f2bf(float x) {
  __bf16 b = (__bf16)x;
  return __builtin_bit_cast(u16, b);
}
__device__ __forceinline__ unsigned int pk2(float a, float b) {
  return (unsigned int)f2bf(a) | ((unsigned int)f2bf(b) << 16);
}
__device__ __forceinline__ float sigf(float x) {
  return __fdividef(1.0f, 1.0f + __expf(-x));
}
__device__ __forceinline__ float tanhf_(float x) {
  return 1.0f - __fdividef(2.0f, __expf(2.0f * x) + 1.0f);
}
__device__ __forceinline__ void wg_barrier_lds() {
  asm volatile("s_waitcnt lgkmcnt(0)" ::: "memory");
  __builtin_amdgcn_s_barrier();
}

__global__ void prep_weights(const float* __restrict__ Whh, const float* __restrict__ Wih,
                             const float* __restrict__ Wout, const float* __restrict__ Wlat,
                             uint4* __restrict__ ws) {
  int i = blockIdx.x * 256 + threadIdx.x;
  if (i >= PREP1_N) return;
  int l = i & 63;
  int c16 = l & 15, g4 = l >> 4;
  const float* src;
  if (i < WIH_O) {
    int t = (i >> 6) & 7, j = i >> 9;
    src = Whh + (j * 16 + c16) * 256 + t * 32 + 8 * g4;
  } else if (i < WOUT_O) {
    int ii = i - WIH_O;
    int j = ii >> 6;
    src = Wih + (j * 16 + c16) * 32 + 8 * g4;
  } else if (i < WLAT_O) {
    int ii = i - WOUT_O;
    int t = (ii >> 6) & 7, j = ii >> 9;
    src = Wout + (j * 16 + c16) * 256 + t * 32 + 8 * g4;
  } else {
    int ii = i - WLAT_O;
    int t = (ii >> 6) & 1, j = ii >> 7;
    src = Wlat + (j * 16 + c16) * 64 + t * 32 + 8 * g4;
  }
  uint4 P;
  P.x = pk2(src[0], src[1]);
  P.y = pk2(src[2], src[3]);
  P.z = pk2(src[4], src[5]);
  P.w = pk2(src[6], src[7]);
  ws[i] = P;
}

__global__ void prep_wt(const float* __restrict__ Wsig, unsigned short* __restrict__ Wt) {
  __shared__ float tile[32][257];
  int f = blockIdx.x >> 3, hb = blockIdx.x & 7;
  int tid = threadIdx.x;
  const float* src = Wsig + f * (HDIM * SLEN) + hb * 32 * 256;
#pragma unroll
  for (int i = 0; i < 32; ++i) tile[i][tid] = src[i * 256 + tid];
  __syncthreads();
  int s = tid;
  unsigned short tmp[32];
#pragma unroll
  for (int h = 0; h < 32; ++h) tmp[h] = f2bf(tile[h][s]);
  uint4* dst = (uint4*)(Wt + f * 65536 + s * 256 + hb * 32);
  const uint4* tsrc = (const uint4*)tmp;
#pragma unroll
  for (int j = 0; j < 4; ++j) dst[j] = tsrc[j];
}

// Persistent LSTM scan: 64 WGs x 16 batch rows, 8 waves (512 thr), 256 steps.
// __launch_bounds__(512,1): ~512-reg unified budget per wave. Wave w owns
// j-pairs jjA=2w, jjB=2w+1 across all 4 gates. The wave's ENTIRE W_hh slice
// (64 frags = 256 regs -> AGPRs, MFMA reads them directly) + W_ih (32 regs)
// is register-resident: the scan loop has ZERO weight memory traffic.
__global__ __launch_bounds__(512, 1) void lstm_scan(
    const float* __restrict__ z, const float* __restrict__ b_lat,
    const float* __restrict__ b_ih, const float* __restrict__ b_hh,
    const float* __restrict__ b_out,
    const uint4* __restrict__ ws, unsigned short* __restrict__ hst,
    float* __restrict__ out) {
  __shared__ __align__(16) uint4 woutb[1024];             // 16KB
  __shared__ __align__(16) u16 hbuf[2][16][256];          // 16KB (swizzled)
  __shared__ __align__(16) u16 thbuf[16][256];            // 8KB  (swizzled; z-stage)
  __shared__ __align__(16) u16 xbuf[2][16][32];           // 2KB
  __shared__ __align__(16) float mubuf[16][16][32];       // 32KB

  const int tid = threadIdx.x, w = tid >> 6, l = tid & 63;
  const int c16 = l & 15, g4 = l >> 4, r0 = g4 * 4;
  const int wg = blockIdx.x;
  const int swz = (c16 & 7) << 3;
  const int jjA = 2 * w, jjB = 2 * w + 1;

  if (tid < 1024) { woutb[tid] = ws[WOUT_O + tid]; woutb[tid + 512] = ws[WOUT_O + tid + 512]; }

  // ---- register/AGPR-resident weights: W_hh (64 frags) + W_ih (8 frags) ----
  uint4 whA[4][8], whB[4][8], wiA[4], wiB[4];
#pragma unroll
  for (int g = 0; g < 4; ++g) {
#pragma unroll
    for (int kt = 0; kt < 8; ++kt) {
      whA[g][kt] = ws[WHH_O + ((g * 16 + jjA) * 8 + kt) * 64 + l];
      whB[g][kt] = ws[WHH_O + ((g * 16 + jjB) * 8 + kt) * 64 + l];
    }
    wiA[g] = ws[WIH_O + (g * 16 + jjA) * 64 + l];
    wiB[g] = ws[WIH_O + (g * 16 + jjB) * 64 + l];
  }

  float biasA[4], biasB[4];
#pragma unroll
  for (int g = 0; g < 4; ++g) {
    int nA = (g * 16 + jjA) * 16 + c16;
    int nB = (g * 16 + jjB) * 16 + c16;
    biasA[g] = b_ih[nA] + b_hh[nA];
    biasB[g] = b_ih[nB] + b_hh[nB];
  }
  const float bo = (w < 2) ? b_out[w * 16 + c16] : 0.f;

  // hoisted LDS element offsets
  const int eo0 = (0 * 32 + 8 * g4) ^ swz, eo1 = (1 * 32 + 8 * g4) ^ swz;
  const int eo2 = (2 * 32 + 8 * g4) ^ swz, eo3 = (3 * 32 + 8 * g4) ^ swz;
  const int eo4 = (4 * 32 + 8 * g4) ^ swz, eo5 = (5 * 32 + 8 * g4) ^ swz;
  const int eo6 = (6 * 32 + 8 * g4) ^ swz, eo7 = (7 * 32 + 8 * g4) ^ swz;
  const int ca = jjA * 16 + c16, cb = jjB * 16 + c16;
  int soA[4], soB[4];
#pragma unroll
  for (int v = 0; v < 4; ++v) {
    soA[v] = ca ^ (((r0 + v) & 7) << 3);
    soB[v] = cb ^ (((r0 + v) & 7) << 3);
  }

  // ---- init: z -> thbuf staging, x0 = 0 ----
  for (int idx = tid; idx < 1024; idx += 512)
    thbuf[idx >> 6][idx & 63] = f2bf(z[(wg * 16 + (idx >> 6)) * 64 + (idx & 63)]);
  xbuf[0][tid >> 5][tid & 31] = 0;
  __syncthreads();

  // hc = z @ W_lat^T + b_lat : wave w computes h/c tiles for jjA, jjB
  float cstA[4], cstB[4];
  {
    bf16x8 za0 = *reinterpret_cast<const bf16x8*>(&thbuf[c16][8 * g4]);
    bf16x8 za1 = *reinterpret_cast<const bf16x8*>(&thbuf[c16][32 + 8 * g4]);
    float bhA = b_lat[ca], bhB = b_lat[cb];
    float bcA = b_lat[256 + ca], bcB = b_lat[256 + cb];
    f32x4 ahA = {bhA, bhA, bhA, bhA}, ahB = {bhB, bhB, bhB, bhB};
    f32x4 acA = {bcA, bcA, bcA, bcA}, acB = {bcB, bcB, bcB, bcB};
    ahA = MFMA(za0, *reinterpret_cast<const bf16x8*>(ws + WLAT_O + (jjA * 2 + 0) * 64 + l), ahA, 0, 0, 0);
    ahA = MFMA(za1, *reinterpret_cast<const bf16x8*>(ws + WLAT_O + (jjA * 2 + 1) * 64 + l), ahA, 0, 0, 0);
    ahB = MFMA(za0, *reinterpret_cast<const bf16x8*>(ws + WLAT_O + (jjB * 2 + 0) * 64 + l), ahB, 0, 0, 0);
    ahB = MFMA(za1, *reinterpret_cast<const bf16x8*>(ws + WLAT_O + (jjB * 2 + 1) * 64 + l), ahB, 0, 0, 0);
    acA = MFMA(za0, *reinterpret_cast<const bf16x8*>(ws + WLAT_O + ((16 + jjA) * 2 + 0) * 64 + l), acA, 0, 0, 0);
    acA = MFMA(za1, *reinterpret_cast<const bf16x8*>(ws + WLAT_O + ((16 + jjA) * 2 + 1) * 64 + l), acA, 0, 0, 0);
    acB = MFMA(za0, *reinterpret_cast<const bf16x8*>(ws + WLAT_O + ((16 + jjB) * 2 + 0) * 64 + l), acB, 0, 0, 0);
    acB = MFMA(za1, *reinterpret_cast<const bf16x8*>(ws + WLAT_O + ((16 + jjB) * 2 + 1) * 64 + l), acB, 0, 0, 0);
#pragma unroll
    for (int v = 0; v < 4; ++v) {
      cstA[v] = acA[v]; cstB[v] = acB[v];
      hbuf[0][r0 + v][soA[v]] = f2bf(ahA[v]);
      hbuf[0][r0 + v][soB[v]] = f2bf(ahB[v]);
    }
  }
  __syncthreads();

  // ---- the scan ----
  for (int s = 0; s < SLEN; ++s) {
    const int pb = s & 1;
    const u16* hrd = &hbuf[pb][0][0];

    f32x4 aA[4], aB[4];
#pragma unroll
    for (int g = 0; g < 4; ++g) {
      aA[g] = (f32x4){biasA[g], biasA[g], biasA[g], biasA[g]};
      aB[g] = (f32x4){biasB[g], biasB[g], biasB[g], biasB[g]};
    }
    __builtin_amdgcn_s_setprio(1);
    {
      bf16x8 afr;
      afr = *reinterpret_cast<const bf16x8*>(hrd + c16 * 256 + eo0);
#pragma unroll
      for (int g = 0; g < 4; ++g) { aA[g] = MFMA(afr, BC(whA[g][0]), aA[g], 0, 0, 0); aB[g] = MFMA(afr, BC(whB[g][0]), aB[g], 0, 0, 0); }
      afr = *reinterpret_cast<const bf16x8*>(hrd + c16 * 256 + eo1);
#pragma unroll
      for (int g = 0; g < 4; ++g) { aA[g] = MFMA(afr, BC(whA[g][1]), aA[g], 0, 0, 0); aB[g] = MFMA(afr, BC(whB[g][1]), aB[g], 0, 0, 0); }
      afr = *reinterpret_cast<const bf16x8*>(hrd + c16 * 256 + eo2);
#pragma unroll
      for (int g = 0; g < 4; ++g) { aA[g] = MFMA(afr, BC(whA[g][2]), aA[g], 0, 0, 0); aB[g] = MFMA(afr, BC(whB[g][2]), aB[g], 0, 0, 0); }
      afr = *reinterpret_cast<const bf16x8*>(hrd + c16 * 256 + eo3);
#pragma unroll
      for (int g = 0; g < 4; ++g) { aA[g] = MFMA(afr, BC(whA[g][3]), aA[g], 0, 0, 0); aB[g] = MFMA(afr, BC(whB[g][3]), aB[g], 0, 0, 0); }
      afr = *reinterpret_cast<const bf16x8*>(hrd + c16 * 256 + eo4);
#pragma unroll
      for (int g = 0; g < 4; ++g) { aA[g] = MFMA(afr, BC(whA[g][4]), aA[g], 0, 0, 0); aB[g] = MFMA(afr, BC(whB[g][4]), aB[g], 0, 0, 0); }
      afr = *reinterpret_cast<const bf16x8*>(hrd + c16 * 256 + eo5);
#pragma unroll
      for (int g = 0; g < 4; ++g) { aA[g] = MFMA(afr, BC(whA[g][5]), aA[g], 0, 0, 0); aB[g] = MFMA(afr, BC(whB[g][5]), aB[g], 0, 0, 0); }
      afr = *reinterpret_cast<const bf16x8*>(hrd + c16 * 256 + eo6);
#pragma unroll
      for (int g = 0; g < 4; ++g) { aA[g] = MFMA(afr, BC(whA[g][6]), aA[g], 0, 0, 0); aB[g] = MFMA(afr, BC(whB[g][6]), aB[g], 0, 0, 0); }
      afr = *reinterpret_cast<const bf16x8*>(hrd + c16 * 256 + eo7);
#pragma unroll
      for (int g = 0; g < 4; ++g) { aA[g] = MFMA(afr, BC(whA[g][7]), aA[g], 0, 0, 0); aB[g] = MFMA(afr, BC(whB[g][7]), aB[g], 0, 0, 0); }
      bf16x8 xfr = *reinterpret_cast<const bf16x8*>(&xbuf[pb][c16][8 * g4]);
#pragma unroll
      for (int g = 0; g < 4; ++g) { aA[g] = MFMA(xfr, BC(wiA[g]), aA[g], 0, 0, 0); aB[g] = MFMA(xfr, BC(wiB[g]), aB[g], 0, 0, 0); }
    }
    __builtin_amdgcn_s_setprio(0);

    // elementwise: lane owns 2 h-cols x 4 batch rows
#pragma unroll
    for (int v = 0; v < 4; ++v) {
      float cc, hh, th;
      cc = sigf(aA[1][v]) * cstA[v] + sigf(aA[0][v]) * tanhf_(aA[2][v]);
      cstA[v] = cc;
      hh = sigf(aA[3][v]) * tanhf_(cc);
      th = tanhf_(hh);
      hbuf[pb ^ 1][r0 + v][soA[v]] = f2bf(hh);
      thbuf[r0 + v][soA[v]] = f2bf(th);
      cc = sigf(aB[1][v]) * cstB[v] + sigf(aB[0][v]) * tanhf_(aB[2][v]);
      cstB[v] = cc;
      hh = sigf(aB[3][v]) * tanhf_(cc);
      th = tanhf_(hh);
      hbuf[pb ^ 1][r0 + v][soB[v]] = f2bf(hh);
      thbuf[r0 + v][soB[v]] = f2bf(th);
    }
    wg_barrier_lds();  // B1: h_{s+1}/th_{s+1} visible

    if (w < 2) {
      // x-GEMM: x_{s+1} = tanh(h_{s+1}) @ W_out^T ; mu col s
      f32x4 xacc = {bo, bo, bo, bo};
      xacc = MFMA(*reinterpret_cast<const bf16x8*>(&thbuf[c16][eo0]), BC(woutb[(w * 8 + 0) * 64 + l]), xacc, 0, 0, 0);
      xacc = MFMA(*reinterpret_cast<const bf16x8*>(&thbuf[c16][eo1]), BC(woutb[(w * 8 + 1) * 64 + l]), xacc, 0, 0, 0);
      xacc = MFMA(*reinterpret_cast<const bf16x8*>(&thbuf[c16][eo2]), BC(woutb[(w * 8 + 2) * 64 + l]), xacc, 0, 0, 0);
      xacc = MFMA(*reinterpret_cast<const bf16x8*>(&thbuf[c16][eo3]), BC(woutb[(w * 8 + 3) * 64 + l]), xacc, 0, 0, 0);
      xacc = MFMA(*reinterpret_cast<const bf16x8*>(&thbuf[c16][eo4]), BC(woutb[(w * 8 + 4) * 64 + l]), xacc, 0, 0, 0);
      xacc = MFMA(*reinterpret_cast<const bf16x8*>(&thbuf[c16][eo5]), BC(woutb[(w * 8 + 5) * 64 + l]), xacc, 0, 0, 0);
      xacc = MFMA(*reinterpret_cast<const bf16x8*>(&thbuf[c16][eo6]), BC(woutb[(w * 8 + 6) * 64 + l]), xacc, 0, 0, 0);
      xacc = MFMA(*reinterpret_cast<const bf16x8*>(&thbuf[c16][eo7]), BC(woutb[(w * 8 + 7) * 64 + l]), xacc, 0, 0, 0);
      const int f = w * 16 + c16;
      const int sw = s & 15;
#pragma unroll
      for (int v = 0; v < 4; ++v) {
        xbuf[pb ^ 1][r0 + v][f] = f2bf(xacc[v]);
        mubuf[sw][r0 + v][f] = xacc[v];
      }
    } else if (w < 6) {
      // h_{s+1} -> hst (coalesced bf16, fire-and-forget)
      int base = (w - 2) * 64 + l;
#pragma unroll
      for (int rep = 0; rep < 2; ++rep) {
        int task = base + rep * 256;
        int r = task >> 5, h0 = (task & 31) * 8;
        uint4 d = *reinterpret_cast<const uint4*>(&hbuf[pb ^ 1][r][h0 ^ ((r & 7) << 3)]);
        *reinterpret_cast<uint4*>(hst + ((wg * 16 + r) << 16) + (s << 8) + h0) = d;
      }
    }
    wg_barrier_lds();  // B2: xbuf/mubuf ready

    if ((s & 15) == 15) {
      // flush 16 steps of mu: thread (b,f) writes 16 consecutive s -> 64B line
      int b = tid >> 5, f = tid & 31;
      float* dst = out + ((wg * 16 + b) << 13) + (f << 8) + (s - 15);
#pragma unroll
      for (int j4 = 0; j4 < 4; ++j4) {
        f32x4 vv;
#pragma unroll
        for (int jj = 0; jj < 4; ++jj) vv[jj] = mubuf[j4 * 4 + jj][b][f];
        *reinterpret_cast<f32x4*>(dst + j4 * 4) = vv;
      }
    }
  }
}

// sigma = softplus(hs_flat @ W_sig^T + b_sig)
__global__ __launch_bounds__(512) void sigma_gemm(
    const unsigned short* __restrict__ hst, const unsigned short* __restrict__ Wt,
    const float* __restrict__ b_sig, float* __restrict__ out) {
  __shared__ float sred[8][16][32];
  const int tid = threadIdx.x;
  const int w = tid >> 6;
  const int l = tid & 63;
  const int c16 = l & 15;
  const int g4 = l >> 4;
  const int wg = blockIdx.x;

  const unsigned short* ap =
      hst + (((wg << 2) + (c16 & 3)) << 16) + ((w * 32) << 8) + (g4 << 3);
  const unsigned short* bp0 = Wt + (c16 << 16) + ((w * 32) << 8) + (g4 << 3);
  const unsigned short* bp1 = Wt + ((16 + c16) << 16) + ((w * 32) << 8) + (g4 << 3);

  f32x4 a0 = {0.f, 0.f, 0.f, 0.f}, a1 = {0.f, 0.f, 0.f, 0.f};
#pragma unroll 8
  for (int kk = 0; kk < 256; ++kk) {
    int off = ((kk >> 3) << 8) + ((kk & 7) << 5);
    bf16x8 av = *reinterpret_cast<const bf16x8*>(ap + off);
    a0 = MFMA(av, *reinterpret_cast<const bf16x8*>(bp0 + off), a0, 0, 0, 0);
    a1 = MFMA(av, *reinterpret_cast<const bf16x8*>(bp1 + off), a1, 0, 0, 0);
  }
#pragma unroll
  for (int v = 0; v < 4; ++v) {
    sred[w][g4 * 4 + v][c16] = a0[v];
    sred[w][g4 * 4 + v][16 + c16] = a1[v];
  }
  __syncthreads();
  int b = tid >> 5, f = tid & 31;
  if (b < 4) {
    float acc = b_sig[f];
#pragma unroll
    for (int ww = 0; ww < 8; ++ww) acc += sred[ww][b][f];
    float sp = fmaxf(acc, 0.0f) + log1pf(__expf(-fabsf(acc)));
    out[BATCH * NF * SLEN + ((wg << 2) + b) * NF + f] = sp;
  }
}

extern "C" void kernel_launch(void* const* d_in, const int* in_sizes, int n_in,
                              void* d_out, int out_size, void* d_ws, size_t ws_size,
                              hipStream_t stream) {
  (void)in_sizes; (void)n_in; (void)out_size; (void)ws_size;
  const float* z     = (const float*)d_in[0];
  const float* W_lat = (const float*)d_in[1];
  const float* b_lat = (const float*)d_in[2];
  const float* W_ih  = (const float*)d_in[3];
  const float* b_ih  = (const float*)d_in[4];
  const float* W_hh  = (const float*)d_in[5];
  const float* b_hh  = (const float*)d_in[6];
  const float* W_out = (const float*)d_in[7];
  const float* b_out = (const float*)d_in[8];
  const float* W_sig = (const float*)d_in[9];
  const float* b_sig = (const float*)d_in[10];
  char* wsb = (char*)d_ws;
  uint4* ws = (uint4*)wsb;
  unsigned short* Wt  = (unsigned short*)(wsb + WT_BYTE);
  unsigned short* hst = (unsigned short*)(wsb + HST_BYTE);
  float* out = (float*)d_out;

  prep_weights<<<(PREP1_N + 255) / 256, 256, 0, stream>>>(W_hh, W_ih, W_out, W_lat, ws);
  prep_wt<<<256, 256, 0, stream>>>(W_sig, Wt);
  lstm_scan<<<64, 512, 0, stream>>>(z, b_lat, b_ih, b_hh, b_out, ws, hst, out);
  sigma_gemm<<<256, 512, 0, stream>>>(hst, Wt, b_sig, out);
}

// Round 17
// 2945.143 us; speedup vs baseline: 1.1694x; 1.1694x over previous
//
#include <hip/hip_runtime.h>

#define NF 32
#define HDIM 256
#define SLEN 256
#define BATCH 1024

typedef float f32x4 __attribute__((ext_vector_type(4)));
typedef __bf16 bf16x8 __attribute__((ext_vector_type(8)));
typedef unsigned short u16;

#define MFMA __builtin_amdgcn_mfma_f32_16x16x32_bf16
#define BC(x) __builtin_bit_cast(bf16x8, x)

// ---- ws layout ----
#define WHH_O 0       // 64 j * 8 t * 64 l  = 32768 slots
#define WIH_O 32768   // 64 j * 64 l        =  4096
#define WOUT_O 36864  //  2 j * 8 t * 64 l  =  1024
#define WLAT_O 37888  // 32 j * 2 t * 64 l  =  4096
#define PREP1_N 41984
#define WT_BYTE (1u << 20)
#define HST_BYTE (8u << 20)

__device__ __forceinline__ u16 f2bf(float x) {
  __bf16 b = (__bf16)x;                 // RNE; pairs into v_cvt_pk_bf16_f32
  return __builtin_bit_cast(u16, b);
}
__device__ __forceinline__ unsigned int pk2(float a, float b) {
  return (unsigned int)f2bf(a) | ((unsigned int)f2bf(b) << 16);
}
__device__ __forceinline__ float sigf(float x) {
  return __fdividef(1.0f, 1.0f + __expf(-x));
}
__device__ __forceinline__ float tanhf_(float x) {
  return 1.0f - __fdividef(2.0f, __expf(2.0f * x) + 1.0f);
}

// Workgroup barrier WITHOUT the vmcnt(0) drain __syncthreads() emits.
__device__ __forceinline__ void wg_barrier_lds() {
  asm volatile("s_waitcnt lgkmcnt(0)" ::: "memory");
  __builtin_amdgcn_s_barrier();
}

__global__ void prep_weights(const float* __restrict__ Whh, const float* __restrict__ Wih,
                             const float* __restrict__ Wout, const float* __restrict__ Wlat,
                             uint4* __restrict__ ws) {
  int i = blockIdx.x * 256 + threadIdx.x;
  if (i >= PREP1_N) return;
  int l = i & 63;
  int c16 = l & 15, g4 = l >> 4;
  const float* src;
  if (i < WIH_O) {
    int t = (i >> 6) & 7, j = i >> 9;
    src = Whh + (j * 16 + c16) * 256 + t * 32 + 8 * g4;
  } else if (i < WOUT_O) {
    int ii = i - WIH_O;
    int j = ii >> 6;
    src = Wih + (j * 16 + c16) * 32 + 8 * g4;
  } else if (i < WLAT_O) {
    int ii = i - WOUT_O;
    int t = (ii >> 6) & 7, j = ii >> 9;
    src = Wout + (j * 16 + c16) * 256 + t * 32 + 8 * g4;
  } else {
    int ii = i - WLAT_O;
    int t = (ii >> 6) & 1, j = ii >> 7;
    src = Wlat + (j * 16 + c16) * 64 + t * 32 + 8 * g4;
  }
  uint4 P;
  P.x = pk2(src[0], src[1]);
  P.y = pk2(src[2], src[3]);
  P.z = pk2(src[4], src[5]);
  P.w = pk2(src[6], src[7]);
  ws[i] = P;
}

__global__ void prep_wt(const float* __restrict__ Wsig, unsigned short* __restrict__ Wt) {
  __shared__ float tile[32][257];
  int f = blockIdx.x >> 3, hb = blockIdx.x & 7;
  int tid = threadIdx.x;  // 256
  const float* src = Wsig + f * (HDIM * SLEN) + hb * 32 * 256;
#pragma unroll
  for (int i = 0; i < 32; ++i) tile[i][tid] = src[i * 256 + tid];
  __syncthreads();
  int s = tid;
  unsigned short tmp[32];
#pragma unroll
  for (int h = 0; h < 32; ++h) tmp[h] = f2bf(tile[h][s]);
  uint4* dst = (uint4*)(Wt + f * 65536 + s * 256 + hb * 32);
  const uint4* tsrc = (const uint4*)tmp;
#pragma unroll
  for (int j = 0; j < 4; ++j) dst[j] = tsrc[j];
}

// Persistent LSTM scan: 64 WGs x 16 batch rows, 16 waves, 256 steps.
// r12 structure (the empirical best): W_hh streamed from L2 via a 2-ahead
// rolling register pipeline inside the kt loop (the one form the allocator
// keeps at FETCH~33MB), lgkm-only barriers, x-GEMM + hst copy in phase 3.
// Deltas vs r12: hoisted LDS offsets; mu flush moved to waves 8-15.
__global__ __launch_bounds__(1024, 4) void lstm_scan(
    const float* __restrict__ z, const float* __restrict__ b_lat,
    const float* __restrict__ b_ih, const float* __restrict__ b_hh,
    const float* __restrict__ b_out,
    const uint4* __restrict__ ws, unsigned short* __restrict__ hst,
    float* __restrict__ out) {
  __shared__ __align__(16) uint4 wihl[4096];              // 64KB W_ih frags
  __shared__ __align__(16) uint4 woutb[1024];             // 16KB W_out frags
  __shared__ __align__(16) u16 hbuf[2][16][256];          // 16KB (swizzled)
  __shared__ __align__(16) u16 thbuf[16][256];            // 8KB (swizzled; z-stage)
  __shared__ __align__(16) u16 xbuf[2][16][32];           // 2KB
  __shared__ __align__(16) float mubuf[16][16][32];       // 32KB

  const int tid = threadIdx.x, w = tid >> 6, l = tid & 63;
  const int c16 = l & 15, g4 = l >> 4, r0 = g4 * 4;
  const int wg = blockIdx.x;
  const int swz = (c16 & 7) << 3;

  // one-time LDS fills
  for (int i = tid; i < 4096; i += 1024) wihl[i] = ws[WIH_O + i];
  if (tid < 1024) woutb[tid] = ws[WOUT_O + tid];

  // streamed W_hh bases, biased at kt=4 so imm offsets (kt-4)*1024 fit +-4096
  const uint4* bs[4];
#pragma unroll
  for (int gi = 0; gi < 4; ++gi)
    bs[gi] = ws + WHH_O + ((gi * 16 + w) * 8 + 4) * 64 + l;

  float biasv[4];
#pragma unroll
  for (int gi = 0; gi < 4; ++gi) {
    int n = (gi * 16 + w) * 16 + c16;
    biasv[gi] = b_ih[n] + b_hh[n];
  }
  const int jn = w - 14;
  const float bo = (w >= 14) ? b_out[jn * 16 + c16] : 0.f;
  const int hc = w * 16 + c16;

  // hoisted LDS element offsets (zero in-loop addr VALU)
  int eoff[8];
#pragma unroll
  for (int kt = 0; kt < 8; ++kt) eoff[kt] = (kt * 32 + 8 * g4) ^ swz;
  int soff[4];
#pragma unroll
  for (int v = 0; v < 4; ++v) soff[v] = hc ^ (((r0 + v) & 7) << 3);

  // ---- init: z -> thbuf staging, x0 = 0 ----
  thbuf[tid >> 6][tid & 63] = f2bf(z[(wg * 16 + (tid >> 6)) * 64 + (tid & 63)]);
  if (tid < 512) xbuf[0][tid >> 5][tid & 31] = 0;
  __syncthreads();

  // hc = z @ W_lat^T + b_lat : wave w computes h-tile j=w, c-tile j=16+w
  float cst[4];
  {
    bf16x8 za0 = *reinterpret_cast<const bf16x8*>(&thbuf[c16][8 * g4]);
    bf16x8 za1 = *reinterpret_cast<const bf16x8*>(&thbuf[c16][32 + 8 * g4]);
    float blh = b_lat[w * 16 + c16];
    float blc = b_lat[256 + w * 16 + c16];
    f32x4 ah = {blh, blh, blh, blh}, ac = {blc, blc, blc, blc};
    ah = MFMA(za0, *reinterpret_cast<const bf16x8*>(ws + WLAT_O + (w * 2 + 0) * 64 + l), ah, 0, 0, 0);
    ah = MFMA(za1, *reinterpret_cast<const bf16x8*>(ws + WLAT_O + (w * 2 + 1) * 64 + l), ah, 0, 0, 0);
    ac = MFMA(za0, *reinterpret_cast<const bf16x8*>(ws + WLAT_O + ((16 + w) * 2 + 0) * 64 + l), ac, 0, 0, 0);
    ac = MFMA(za1, *reinterpret_cast<const bf16x8*>(ws + WLAT_O + ((16 + w) * 2 + 1) * 64 + l), ac, 0, 0, 0);
#pragma unroll
    for (int v = 0; v < 4; ++v) {
      cst[v] = ac[v];
      hbuf[0][r0 + v][soff[v]] = f2bf(ah[v]);
    }
  }
  __syncthreads();

  // rolling prefetch: preload kt0, kt1
  uint4 pf0[4], pf1[4];
#pragma unroll
  for (int gi = 0; gi < 4; ++gi) pf0[gi] = bs[gi][(0 - 4) * 64];
#pragma unroll
  for (int gi = 0; gi < 4; ++gi) pf1[gi] = bs[gi][(1 - 4) * 64];

  // ---- the scan ----
  for (int s = 0; s < SLEN; ++s) {
    const int pb = s & 1;
    // phase 1: gates — rolling 2-ahead W_hh stream, static indices
    f32x4 acc[4];
#pragma unroll
    for (int gi = 0; gi < 4; ++gi)
      acc[gi] = (f32x4){biasv[gi], biasv[gi], biasv[gi], biasv[gi]};
#pragma unroll
    for (int kt = 0; kt < 8; ++kt) {
      uint4 pf2[4];
      const int ktn = (kt + 2) & 7;   // kt6/kt7 issue kt0/kt1 for the NEXT step
#pragma unroll
      for (int gi = 0; gi < 4; ++gi) pf2[gi] = bs[gi][(ktn - 4) * 64];
      bf16x8 afr = *reinterpret_cast<const bf16x8*>(&hbuf[pb][c16][eoff[kt]]);
#pragma unroll
      for (int gi = 0; gi < 4; ++gi)
        acc[gi] = MFMA(afr, BC(pf0[gi]), acc[gi], 0, 0, 0);
#pragma unroll
      for (int gi = 0; gi < 4; ++gi) { pf0[gi] = pf1[gi]; pf1[gi] = pf2[gi]; }
    }
    {
      bf16x8 xfr = *reinterpret_cast<const bf16x8*>(&xbuf[pb][c16][8 * g4]);
#pragma unroll
      for (int gi = 0; gi < 4; ++gi)
        acc[gi] = MFMA(xfr, BC(wihl[(gi * 16 + w) * 64 + l]), acc[gi], 0, 0, 0);
    }
    // elementwise: lane owns 4 batch rows x 1 h-col
#pragma unroll
    for (int v = 0; v < 4; ++v) {
      float iv = acc[0][v];
      float fv = acc[1][v];
      float gv = acc[2][v];
      float ov = acc[3][v];
      float cc = sigf(fv) * cst[v] + sigf(iv) * tanhf_(gv);
      cst[v] = cc;
      float hh = sigf(ov) * tanhf_(cc);
      float th = tanhf_(hh);
      hbuf[pb ^ 1][r0 + v][soff[v]] = f2bf(hh);
      thbuf[r0 + v][soff[v]] = f2bf(th);
    }
    wg_barrier_lds();  // B1 (no vmcnt drain)
    // phase 3: waves 14-15: x_{s+1} = tanh(h_{s+1}) @ W_out^T -> xbuf + mubuf;
    //          waves 0-7:   h_{s+1} -> hst (coalesced bf16, fire-and-forget)
    if (w >= 14) {
      f32x4 xacc = {bo, bo, bo, bo};
#pragma unroll
      for (int t = 0; t < 8; ++t) {
        bf16x8 ta = *reinterpret_cast<const bf16x8*>(&thbuf[c16][eoff[t]]);
        xacc = MFMA(ta, BC(woutb[(jn * 8 + t) * 64 + l]), xacc, 0, 0, 0);
      }
      const int f = jn * 16 + c16;
      const int sw = s & 15;
#pragma unroll
      for (int v = 0; v < 4; ++v) {
        xbuf[pb ^ 1][r0 + v][f] = f2bf(xacc[v]);
        mubuf[sw][r0 + v][f] = xacc[v];
      }
    } else if (w < 8) {
      int r = tid >> 5;
      int h0 = (tid & 31) * 8;
      uint4 d = *reinterpret_cast<const uint4*>(&hbuf[pb ^ 1][r][h0 ^ ((r & 7) << 3)]);
      *reinterpret_cast<uint4*>(hst + ((wg * 16 + r) << 16) + (s << 8) + h0) = d;
    }
    wg_barrier_lds();  // B2 (no vmcnt drain)
    if ((s & 15) == 15 && tid >= 512) {
      // flush 16 steps of mu on waves 8-15 (idle in phase 3); thread (b,f)
      // writes 16 consecutive s -> one 64B line
      int t5 = tid - 512;
      int b = t5 >> 5, f = t5 & 31;
      float* dst = out + ((wg * 16 + b) << 13) + (f << 8) + (s - 15);
#pragma unroll
      for (int j4 = 0; j4 < 4; ++j4) {
        f32x4 vv;
#pragma unroll
        for (int jj = 0; jj < 4; ++jj) vv[jj] = mubuf[j4 * 4 + jj][b][f];
        *reinterpret_cast<f32x4*>(dst + j4 * 4) = vv;
      }
      // safe: next write to these mubuf slots is after B1 of step s+1, and
      // this wave's flush ds_reads are lgkm-drained at that barrier.
    }
  }
}

// sigma = softplus(hs_flat @ W_sig^T + b_sig)
// 256 WGs x 4 batch rows; each wave owns a 8192-wide k-chunk; LDS reduce.
__global__ __launch_bounds__(512) void sigma_gemm(
    const unsigned short* __restrict__ hst, const unsigned short* __restrict__ Wt,
    const float* __restrict__ b_sig, float* __restrict__ out) {
  __shared__ float sred[8][16][32];  // 16KB
  const int tid = threadIdx.x;
  const int w = tid >> 6;
  const int l = tid & 63;
  const int c16 = l & 15;
  const int g4 = l >> 4;
  const int wg = blockIdx.x;

  const unsigned short* ap =
      hst + (((wg << 2) + (c16 & 3)) << 16) + ((w * 32) << 8) + (g4 << 3);
  const unsigned short* bp0 = Wt + (c16 << 16) + ((w * 32) << 8) + (g4 << 3);
  const unsigned short* bp1 = Wt + ((16 + c16) << 16) + ((w * 32) << 8) + (g4 << 3);

  f32x4 a0 = {0.f, 0.f, 0.f, 0.f}, a1 = {0.f, 0.f, 0.f, 0.f};
#pragma unroll 8
  for (int kk = 0; kk < 256; ++kk) {
    int off = ((kk >> 3) << 8) + ((kk & 7) << 5);
    bf16x8 av = *reinterpret_cast<const bf16x8*>(ap + off);
    a0 = MFMA(av, *reinterpret_cast<const bf16x8*>(bp0 + off), a0, 0, 0, 0);
    a1 = MFMA(av, *reinterpret_cast<const bf16x8*>(bp1 + off), a1, 0, 0, 0);
  }
#pragma unroll
  for (int v = 0; v < 4; ++v) {
    sred[w][g4 * 4 + v][c16] = a0[v];
    sred[w][g4 * 4 + v][16 + c16] = a1[v];
  }
  __syncthreads();
  int b = tid >> 5, f = tid & 31;
  if (b < 4) {
    float acc = b_sig[f];
#pragma unroll
    for (int ww = 0; ww < 8; ++ww) acc += sred[ww][b][f];
    float sp = fmaxf(acc, 0.0f) + log1pf(__expf(-fabsf(acc)));
    out[BATCH * NF * SLEN + ((wg << 2) + b) * NF + f] = sp;
  }
}

extern "C" void kernel_launch(void* const* d_in, const int* in_sizes, int n_in,
                              void* d_out, int out_size, void* d_ws, size_t ws_size,
                              hipStream_t stream) {
  (void)in_sizes; (void)n_in; (void)out_size; (void)ws_size;
  const float* z     = (const float*)d_in[0];
  const float* W_lat = (const float*)d_in[1];
  const float* b_lat = (const float*)d_in[2];
  const float* W_ih  = (const float*)d_in[3];
  const float* b_ih  = (const float*)d_in[4];
  const float* W_hh  = (const float*)d_in[5];
  const float* b_hh  = (const float*)d_in[6];
  const float* W_out = (const float*)d_in[7];
  const float* b_out = (const float*)d_in[8];
  const float* W_sig = (const float*)d_in[9];
  const float* b_sig = (const float*)d_in[10];
  char* wsb = (char*)d_ws;
  uint4* ws = (uint4*)wsb;
  unsigned short* Wt  = (unsigned short*)(wsb + WT_BYTE);
  unsigned short* hst = (unsigned short*)(wsb + HST_BYTE);
  float* out = (float*)d_out;

  prep_weights<<<(PREP1_N + 255) / 256, 256, 0, stream>>>(W_hh, W_ih, W_out, W_lat, ws);
  prep_wt<<<256, 256, 0, stream>>>(W_sig, Wt);
  lstm_scan<<<64, 1024, 0, stream>>>(z, b_lat, b_ih, b_hh, b_out, ws, hst, out);
  sigma_gemm<<<256, 512, 0, stream>>>(hst, Wt, b_sig, out);
}